// Round 1
// baseline (281.843 us; speedup 1.0000x reference)
//
#include <hip/hip_runtime.h>
#include <hip/hip_bf16.h>
#include <cstdint>
#include <cstddef>

// Problem constants (fixed by setup_inputs)
#define N_ROWS 2048
#define DIM    512
#define QN     3
#define KQ     8192
#define NCOL   (QN * KQ)   // 24576
#define NCLASS 16

#define BM 128
#define BN 128
#define BK 64

typedef __attribute__((ext_vector_type(8))) short short8;
typedef __attribute__((ext_vector_type(4))) float f32x4;

__device__ inline unsigned short f2bf(float f) {
    uint32_t u = __float_as_uint(f);
    uint32_t r = (u + 0x7FFFu + ((u >> 16) & 1u)) >> 16;
    return (unsigned short)r;
}

// ---------------------------------------------------------------------------
// Kernel 1: L2-normalize rows of x and q_data, cast to bf16.
// One wave (64 threads) per row of 512 floats; 8 floats/lane.
// ---------------------------------------------------------------------------
__global__ __launch_bounds__(64) void norm_cast_kernel(
    const float* __restrict__ x, const float* __restrict__ q,
    unsigned short* __restrict__ xb, unsigned short* __restrict__ qb) {
    int row = blockIdx.x;
    int lane = threadIdx.x;
    const float* src;
    unsigned short* dst;
    if (row < N_ROWS) {
        src = x + (size_t)row * DIM;
        dst = xb + (size_t)row * DIM;
    } else {
        src = q + (size_t)(row - N_ROWS) * DIM;
        dst = qb + (size_t)(row - N_ROWS) * DIM;
    }
    float4 v0 = ((const float4*)src)[lane * 2];
    float4 v1 = ((const float4*)src)[lane * 2 + 1];
    float ss = v0.x*v0.x + v0.y*v0.y + v0.z*v0.z + v0.w*v0.w
             + v1.x*v1.x + v1.y*v1.y + v1.z*v1.z + v1.w*v1.w;
    #pragma unroll
    for (int off = 1; off < 64; off <<= 1)
        ss += __shfl_xor(ss, off, 64);
    float inv = 1.0f / fmaxf(sqrtf(ss), 1e-12f);
    float vals[8] = {v0.x, v0.y, v0.z, v0.w, v1.x, v1.y, v1.z, v1.w};
    short8 o;
    #pragma unroll
    for (int i = 0; i < 8; i++)
        o[i] = (short)f2bf(vals[i] * inv);
    *(short8*)(dst + lane * 8) = o;
}

// ---------------------------------------------------------------------------
// Kernel 2: bf16 MFMA GEMM (M=2048, N=24576, K=512), m97 structure:
// 128x128 tile, BK=64, 4 waves, global_load_lds width-16 staging.
// Fused epilogue: e = exp(4*sim-4), zero-weight masked (q==order &&
// targets[row]==q_targets[order][k]), row-sum via shfl butterfly, atomicAdd
// into S[row].
// ---------------------------------------------------------------------------
__global__ __launch_bounds__(256) void gemm_epilogue_kernel(
    const unsigned short* __restrict__ Xb,   // [2048][512] bf16 bits
    const unsigned short* __restrict__ Qb,   // [24576][512] bf16 bits
    const int* __restrict__ targets,
    const int* __restrict__ q_targets,
    const int* __restrict__ order_p,
    float* __restrict__ S) {

    __shared__ unsigned short As[BM * BK];   // 16 KB
    __shared__ unsigned short Bs[BN * BK];   // 16 KB

    const int tid  = threadIdx.x;
    const int lane = tid & 63;
    const int wave = tid >> 6;               // 0..3
    const int wm = wave >> 1, wn = wave & 1;
    const int quad = lane >> 4;              // 0..3
    const int l15  = lane & 15;

    const int m0 = blockIdx.y * BM;
    const int n0 = blockIdx.x * BN;

    f32x4 acc[4][4];
    #pragma unroll
    for (int i = 0; i < 4; i++)
        #pragma unroll
        for (int j = 0; j < 4; j++)
            acc[i][j] = (f32x4){0.f, 0.f, 0.f, 0.f};

    // Staging geometry: chunk = wave*4+j (0..15); each chunk is a 1 KiB LDS
    // block = 8 rows x 64 cols bf16. Lane l covers row chunk*8 + l/8,
    // cols (l&7)*8 .. +8. LDS dest = base + lane*16 B (wave-uniform rule).
    const int stR = (lane >> 3);        // 0..7
    const int stC = (lane & 7) * 8;     // 0..56

    for (int k0 = 0; k0 < DIM; k0 += BK) {
        #pragma unroll
        for (int j = 0; j < 4; j++) {
            int chunk = wave * 4 + j;                 // 0..15
            int R = chunk * 8 + stR;                  // 0..127
            const unsigned short* ga = Xb + (size_t)(m0 + R) * DIM + k0 + stC;
            const unsigned short* gb = Qb + (size_t)(n0 + R) * DIM + k0 + stC;
            __builtin_amdgcn_global_load_lds(
                (const __attribute__((address_space(1))) unsigned int*)ga,
                (__attribute__((address_space(3))) unsigned int*)&As[chunk * 512 + lane * 8],
                16, 0, 0);
            __builtin_amdgcn_global_load_lds(
                (const __attribute__((address_space(1))) unsigned int*)gb,
                (__attribute__((address_space(3))) unsigned int*)&Bs[chunk * 512 + lane * 8],
                16, 0, 0);
        }
        __syncthreads();

        #pragma unroll
        for (int ks = 0; ks < BK; ks += 32) {
            short8 a[4], b[4];
            #pragma unroll
            for (int mt = 0; mt < 4; mt++)
                a[mt] = *(const short8*)&As[(wm * 64 + mt * 16 + l15) * BK + ks + quad * 8];
            #pragma unroll
            for (int nt = 0; nt < 4; nt++)
                b[nt] = *(const short8*)&Bs[(wn * 64 + nt * 16 + l15) * BK + ks + quad * 8];
            #pragma unroll
            for (int mt = 0; mt < 4; mt++)
                #pragma unroll
                for (int nt = 0; nt < 4; nt++)
                    acc[mt][nt] = __builtin_amdgcn_mfma_f32_16x16x32_bf16(
                        a[mt], b[nt], acc[mt][nt], 0, 0, 0);
        }
        __syncthreads();
    }

    // ---- Epilogue ----
    const int ord  = order_p[0];
    const int qIdx = n0 / KQ;            // block lies entirely within one queue
    const bool isOrd = (qIdx == ord);
    const int kbase = n0 - qIdx * KQ;

    int qtv[4] = {0, 0, 0, 0};
    if (isOrd) {
        #pragma unroll
        for (int nt = 0; nt < 4; nt++)
            qtv[nt] = q_targets[ord * KQ + kbase + wn * 64 + nt * 16 + l15];
    }

    const float LOG2E = 1.44269504088896340736f;
    #pragma unroll
    for (int mt = 0; mt < 4; mt++) {
        int rowb = m0 + wm * 64 + mt * 16 + quad * 4;   // + reg gives the row
        int tg[4] = {0, 0, 0, 0};
        if (isOrd) {
            #pragma unroll
            for (int reg = 0; reg < 4; reg++) tg[reg] = targets[rowb + reg];
        }
        #pragma unroll
        for (int reg = 0; reg < 4; reg++) {
            float s = 0.f;
            #pragma unroll
            for (int nt = 0; nt < 4; nt++) {
                float sim = acc[mt][nt][reg];
                float e = __expf(4.0f * sim - 4.0f);
                if (isOrd && tg[reg] == qtv[nt]) e = 0.f;  // masked entry
                s += e;
            }
            // reduce over the 16 columns held across lanes of this quad
            s += __shfl_xor(s, 1, 64);
            s += __shfl_xor(s, 2, 64);
            s += __shfl_xor(s, 4, 64);
            s += __shfl_xor(s, 8, 64);
            if (l15 == 0)
                atomicAdd(&S[rowb + reg], s);
            (void)LOG2E;
        }
    }
}

// ---------------------------------------------------------------------------
// Kernel 3: count[i] via 16-bin histogram of q_targets[order], then
// loss = mean_i log(S[i] / count[i]).
// ---------------------------------------------------------------------------
__global__ __launch_bounds__(256) void loss_kernel(
    const float* __restrict__ S,
    const int* __restrict__ targets,
    const int* __restrict__ q_targets,
    const int* __restrict__ order_p,
    float* __restrict__ out) {
    __shared__ int hist[NCLASS];
    __shared__ float partial[4];
    int tid = threadIdx.x;
    if (tid < NCLASS) hist[tid] = 0;
    __syncthreads();
    int ord = order_p[0];
    for (int i = tid; i < KQ; i += 256)
        atomicAdd(&hist[q_targets[ord * KQ + i]], 1);
    __syncthreads();
    float local = 0.f;
    for (int i = tid; i < N_ROWS; i += 256) {
        float cnt = (float)(QN * KQ - hist[targets[i]]);
        local += logf(S[i] / cnt);
    }
    #pragma unroll
    for (int off = 1; off < 64; off <<= 1)
        local += __shfl_xor(local, off, 64);
    int wave = tid >> 6, lane = tid & 63;
    if (lane == 0) partial[wave] = local;
    __syncthreads();
    if (tid == 0)
        out[0] = (partial[0] + partial[1] + partial[2] + partial[3]) / (float)N_ROWS;
}

// ---------------------------------------------------------------------------
extern "C" void kernel_launch(void* const* d_in, const int* in_sizes, int n_in,
                              void* d_out, int out_size, void* d_ws, size_t ws_size,
                              hipStream_t stream) {
    const float* x         = (const float*)d_in[0];
    const float* q         = (const float*)d_in[1];
    const int*   targets   = (const int*)d_in[2];
    const int*   q_targets = (const int*)d_in[3];
    const int*   order     = (const int*)d_in[4];
    float* out = (float*)d_out;

    // Workspace layout: S (2048 f32) | Xb (2048*512 bf16) | Qb (24576*512 bf16)
    char* ws = (char*)d_ws;
    float* S = (float*)ws;
    unsigned short* Xb = (unsigned short*)(ws + 8192);
    unsigned short* Qb = (unsigned short*)(ws + 8192 + (size_t)N_ROWS * DIM * 2);

    hipMemsetAsync(S, 0, N_ROWS * sizeof(float), stream);

    norm_cast_kernel<<<N_ROWS + NCOL, 64, 0, stream>>>(x, q, Xb, Qb);

    dim3 grid(NCOL / BN, N_ROWS / BM);
    gemm_epilogue_kernel<<<grid, 256, 0, stream>>>(Xb, Qb, targets, q_targets, order, S);

    loss_kernel<<<1, 256, 0, stream>>>(S, targets, q_targets, order, out);
}

// Round 2
// 207.457 us; speedup vs baseline: 1.3586x; 1.3586x over previous
//
#include <hip/hip_runtime.h>
#include <hip/hip_bf16.h>
#include <cstdint>
#include <cstddef>

// Problem constants (fixed by setup_inputs)
#define N_ROWS 2048
#define DIM    512
#define QN     3
#define KQ     8192
#define NCOL   (QN * KQ)   // 24576
#define NCLASS 16

#define BM 128
#define BN 128
#define BK 64
#define NBLK (NCOL / BN)   // 192 column blocks

typedef __attribute__((ext_vector_type(8))) short short8;
typedef __attribute__((ext_vector_type(4))) float f32x4;

__device__ inline unsigned short f2bf(float f) {
    uint32_t u = __float_as_uint(f);
    uint32_t r = (u + 0x7FFFu + ((u >> 16) & 1u)) >> 16;
    return (unsigned short)r;
}

// ---------------------------------------------------------------------------
// Kernel 1: L2-normalize rows of x and q_data, cast to bf16.
// One wave per row of 512 floats; 4 rows per 256-thread block.
// ---------------------------------------------------------------------------
__global__ __launch_bounds__(256) void norm_cast_kernel(
    const float* __restrict__ x, const float* __restrict__ q,
    unsigned short* __restrict__ xb, unsigned short* __restrict__ qb) {
    int row = blockIdx.x * 4 + (threadIdx.x >> 6);
    int lane = threadIdx.x & 63;
    const float* src;
    unsigned short* dst;
    if (row < N_ROWS) {
        src = x + (size_t)row * DIM;
        dst = xb + (size_t)row * DIM;
    } else {
        src = q + (size_t)(row - N_ROWS) * DIM;
        dst = qb + (size_t)(row - N_ROWS) * DIM;
    }
    float4 v0 = ((const float4*)src)[lane * 2];
    float4 v1 = ((const float4*)src)[lane * 2 + 1];
    float ss = v0.x*v0.x + v0.y*v0.y + v0.z*v0.z + v0.w*v0.w
             + v1.x*v1.x + v1.y*v1.y + v1.z*v1.z + v1.w*v1.w;
    #pragma unroll
    for (int off = 1; off < 64; off <<= 1)
        ss += __shfl_xor(ss, off, 64);
    float inv = 1.0f / fmaxf(sqrtf(ss), 1e-12f);
    float vals[8] = {v0.x, v0.y, v0.z, v0.w, v1.x, v1.y, v1.z, v1.w};
    short8 o;
    #pragma unroll
    for (int i = 0; i < 8; i++)
        o[i] = (short)f2bf(vals[i] * inv);
    *(short8*)(dst + lane * 8) = o;
}

// ---------------------------------------------------------------------------
// Kernel 2: bf16 MFMA GEMM (M=2048, N=24576, K=512), m97 structure.
// Fused epilogue: e = exp(4*sim-4) with mask-weight 0, block-level row
// reduction through LDS, ONE coalesced 128-float store per block into
// P[blockIdx.x][m0..m0+128]. No atomics (round-1 post-mortem: 786K
// device-scope atomicAdds wrote through to HBM -- WRITE_SIZE 12288 KB
// exactly 786432*16B -- and serialized 6144-deep per cache line).
// ---------------------------------------------------------------------------
__global__ __launch_bounds__(256) void gemm_epilogue_kernel(
    const unsigned short* __restrict__ Xb,   // [2048][512] bf16 bits
    const unsigned short* __restrict__ Qb,   // [24576][512] bf16 bits
    const int* __restrict__ targets,
    const int* __restrict__ q_targets,
    const int* __restrict__ order_p,
    float* __restrict__ P) {                 // [NBLK][N_ROWS] partial sums

    __shared__ unsigned short As[BM * BK];   // 16 KB
    __shared__ unsigned short Bs[BN * BK];   // 16 KB

    const int tid  = threadIdx.x;
    const int lane = tid & 63;
    const int wave = tid >> 6;               // 0..3
    const int wm = wave >> 1, wn = wave & 1;
    const int quad = lane >> 4;              // 0..3
    const int l15  = lane & 15;

    const int m0 = blockIdx.y * BM;
    const int n0 = blockIdx.x * BN;

    f32x4 acc[4][4];
    #pragma unroll
    for (int i = 0; i < 4; i++)
        #pragma unroll
        for (int j = 0; j < 4; j++)
            acc[i][j] = (f32x4){0.f, 0.f, 0.f, 0.f};

    // Staging geometry: chunk = wave*4+j (0..15); each chunk is a 1 KiB LDS
    // block = 8 rows x 64 cols bf16. LDS dest = base + lane*16 B.
    const int stR = (lane >> 3);        // 0..7
    const int stC = (lane & 7) * 8;     // 0..56

    for (int k0 = 0; k0 < DIM; k0 += BK) {
        #pragma unroll
        for (int j = 0; j < 4; j++) {
            int chunk = wave * 4 + j;                 // 0..15
            int R = chunk * 8 + stR;                  // 0..127
            const unsigned short* ga = Xb + (size_t)(m0 + R) * DIM + k0 + stC;
            const unsigned short* gb = Qb + (size_t)(n0 + R) * DIM + k0 + stC;
            __builtin_amdgcn_global_load_lds(
                (const __attribute__((address_space(1))) unsigned int*)ga,
                (__attribute__((address_space(3))) unsigned int*)&As[chunk * 512 + lane * 8],
                16, 0, 0);
            __builtin_amdgcn_global_load_lds(
                (const __attribute__((address_space(1))) unsigned int*)gb,
                (__attribute__((address_space(3))) unsigned int*)&Bs[chunk * 512 + lane * 8],
                16, 0, 0);
        }
        __syncthreads();

        #pragma unroll
        for (int ks = 0; ks < BK; ks += 32) {
            short8 a[4], b[4];
            #pragma unroll
            for (int mt = 0; mt < 4; mt++)
                a[mt] = *(const short8*)&As[(wm * 64 + mt * 16 + l15) * BK + ks + quad * 8];
            #pragma unroll
            for (int nt = 0; nt < 4; nt++)
                b[nt] = *(const short8*)&Bs[(wn * 64 + nt * 16 + l15) * BK + ks + quad * 8];
            #pragma unroll
            for (int mt = 0; mt < 4; mt++)
                #pragma unroll
                for (int nt = 0; nt < 4; nt++)
                    acc[mt][nt] = __builtin_amdgcn_mfma_f32_16x16x32_bf16(
                        a[mt], b[nt], acc[mt][nt], 0, 0, 0);
        }
        __syncthreads();
    }

    // ---- Epilogue: exp + mask + block row-reduction, no atomics ----
    const int ord  = order_p[0];
    const int qIdx = n0 / KQ;            // block lies entirely within one queue
    const bool isOrd = (qIdx == ord);
    const int kbase = n0 - qIdx * KQ;

    int qtv[4] = {0, 0, 0, 0};
    if (isOrd) {
        #pragma unroll
        for (int nt = 0; nt < 4; nt++)
            qtv[nt] = q_targets[ord * KQ + kbase + wn * 64 + nt * 16 + l15];
    }

    // Reuse As space (all waves past final __syncthreads of the K-loop).
    float* red = (float*)As;             // red[wn*128 + local_row], 1 KB

    #pragma unroll
    for (int mt = 0; mt < 4; mt++) {
        int rowl = wm * 64 + mt * 16 + quad * 4;        // local row base
        int tg[4] = {0, 0, 0, 0};
        if (isOrd) {
            #pragma unroll
            for (int reg = 0; reg < 4; reg++) tg[reg] = targets[m0 + rowl + reg];
        }
        #pragma unroll
        for (int reg = 0; reg < 4; reg++) {
            float s = 0.f;
            #pragma unroll
            for (int nt = 0; nt < 4; nt++) {
                float sim = acc[mt][nt][reg];
                float e = __expf(4.0f * sim - 4.0f);
                if (isOrd && tg[reg] == qtv[nt]) e = 0.f;  // masked entry
                s += e;
            }
            // reduce over the 16 columns held across lanes of this quad
            s += __shfl_xor(s, 1, 64);
            s += __shfl_xor(s, 2, 64);
            s += __shfl_xor(s, 4, 64);
            s += __shfl_xor(s, 8, 64);
            if (l15 == 0)
                red[wn * 128 + rowl + reg] = s;
        }
    }
    __syncthreads();
    if (tid < 128)
        P[(size_t)blockIdx.x * N_ROWS + m0 + tid] = red[tid] + red[128 + tid];
}

// ---------------------------------------------------------------------------
// Kernel 3: per-row total = sum over 192 partials (coalesced), count via
// 16-bin histogram of q_targets[order], then accumulate mean(log(total/cnt))
// into out via one atomicAdd per block (out pre-zeroed by memsetAsync).
// ---------------------------------------------------------------------------
__global__ __launch_bounds__(256) void reduce_kernel(
    const float* __restrict__ P,
    const int* __restrict__ targets,
    const int* __restrict__ q_targets,
    const int* __restrict__ order_p,
    float* __restrict__ out) {
    __shared__ int hist[NCLASS];
    __shared__ float partial[4];
    int tid = threadIdx.x;
    if (tid < NCLASS) hist[tid] = 0;
    __syncthreads();
    int ord = order_p[0];
    for (int i = tid; i < KQ; i += 256)
        atomicAdd(&hist[q_targets[ord * KQ + i]], 1);
    __syncthreads();

    int r = blockIdx.x * 256 + tid;      // 8 blocks x 256 = 2048 rows
    float total = 0.f;
    for (int nb = 0; nb < NBLK; nb++)
        total += P[(size_t)nb * N_ROWS + r];   // coalesced across threads
    float cnt = (float)(QN * KQ - hist[targets[r]]);
    float v = logf(total / cnt);

    #pragma unroll
    for (int off = 1; off < 64; off <<= 1)
        v += __shfl_xor(v, off, 64);
    int wave = tid >> 6, lane = tid & 63;
    if (lane == 0) partial[wave] = v;
    __syncthreads();
    if (tid == 0)
        atomicAdd(out, (partial[0] + partial[1] + partial[2] + partial[3])
                       * (1.0f / (float)N_ROWS));
}

// ---------------------------------------------------------------------------
extern "C" void kernel_launch(void* const* d_in, const int* in_sizes, int n_in,
                              void* d_out, int out_size, void* d_ws, size_t ws_size,
                              hipStream_t stream) {
    const float* x         = (const float*)d_in[0];
    const float* q         = (const float*)d_in[1];
    const int*   targets   = (const int*)d_in[2];
    const int*   q_targets = (const int*)d_in[3];
    const int*   order     = (const int*)d_in[4];
    float* out = (float*)d_out;

    // Workspace: P (192*2048 f32 = 1.5 MB) | Xb (2 MB bf16) | Qb (24 MB bf16)
    char* ws = (char*)d_ws;
    float* P = (float*)ws;
    unsigned short* Xb = (unsigned short*)(ws + (size_t)NBLK * N_ROWS * 4);
    unsigned short* Qb = Xb + (size_t)N_ROWS * DIM;

    hipMemsetAsync(out, 0, sizeof(float), stream);

    norm_cast_kernel<<<(N_ROWS + NCOL) / 4, 256, 0, stream>>>(x, q, Xb, Qb);

    dim3 grid(NCOL / BN, N_ROWS / BM);
    gemm_epilogue_kernel<<<grid, 256, 0, stream>>>(Xb, Qb, targets, q_targets, order, P);

    reduce_kernel<<<N_ROWS / 256, 256, 0, stream>>>(P, targets, q_targets, order, out);
}

// Round 3
// 204.374 us; speedup vs baseline: 1.3790x; 1.0151x over previous
//
#include <hip/hip_runtime.h>
#include <hip/hip_bf16.h>
#include <cstdint>
#include <cstddef>

// Problem constants (fixed by setup_inputs)
#define N_ROWS 2048
#define DIM    512
#define QN     3
#define KQ     8192
#define NCOL   (QN * KQ)   // 24576
#define NCLASS 16

#define BM 128
#define BN 128
#define BK 64
#define NBLK (NCOL / BN)   // 192 column blocks

typedef __attribute__((ext_vector_type(8))) short short8;
typedef __attribute__((ext_vector_type(4))) float f32x4;

__device__ inline unsigned short f2bf(float f) {
    uint32_t u = __float_as_uint(f);
    uint32_t r = (u + 0x7FFFu + ((u >> 16) & 1u)) >> 16;
    return (unsigned short)r;
}

// ---------------------------------------------------------------------------
// Kernel 1: L2-normalize rows of x and q_data, cast to bf16.
// One wave per row of 512 floats; 4 rows per 256-thread block.
// ---------------------------------------------------------------------------
__global__ __launch_bounds__(256) void norm_cast_kernel(
    const float* __restrict__ x, const float* __restrict__ q,
    unsigned short* __restrict__ xb, unsigned short* __restrict__ qb) {
    int row = blockIdx.x * 4 + (threadIdx.x >> 6);
    int lane = threadIdx.x & 63;
    const float* src;
    unsigned short* dst;
    if (row < N_ROWS) {
        src = x + (size_t)row * DIM;
        dst = xb + (size_t)row * DIM;
    } else {
        src = q + (size_t)(row - N_ROWS) * DIM;
        dst = qb + (size_t)(row - N_ROWS) * DIM;
    }
    float4 v0 = ((const float4*)src)[lane * 2];
    float4 v1 = ((const float4*)src)[lane * 2 + 1];
    float ss = v0.x*v0.x + v0.y*v0.y + v0.z*v0.z + v0.w*v0.w
             + v1.x*v1.x + v1.y*v1.y + v1.z*v1.z + v1.w*v1.w;
    #pragma unroll
    for (int off = 1; off < 64; off <<= 1)
        ss += __shfl_xor(ss, off, 64);
    float inv = 1.0f / fmaxf(sqrtf(ss), 1e-12f);
    float vals[8] = {v0.x, v0.y, v0.z, v0.w, v1.x, v1.y, v1.z, v1.w};
    short8 o;
    #pragma unroll
    for (int i = 0; i < 8; i++)
        o[i] = (short)f2bf(vals[i] * inv);
    *(short8*)(dst + lane * 8) = o;
}

// ---------------------------------------------------------------------------
// Kernel 2: bf16 MFMA GEMM (M=2048, N=24576, K=512), m97 structure with
// XOR-swizzled LDS (round-2 post-mortem: unswizzled 64-elem rows = 128 B =
// exactly 32 banks, so reads hit banks 0-15 only -> 16-way conflict,
// SQ_LDS_BANK_CONFLICT 1.9e7 ~= 31 us/kernel).
// Layout: element (r,k) at LDS r*64 + ((k>>3 ^ (r&7))<<3) + (k&7).
// Staging keeps global_load_lds's fixed lane->LDS mapping and instead
// permutes WHICH 16B global chunk each lane fetches (same 128B segments,
// still coalesced).
// Fused epilogue: e = exp(4*sim-4), mask-weight 0, LDS row-reduce, one
// coalesced 128-float store per block into P.
// ---------------------------------------------------------------------------
__global__ __launch_bounds__(256) void gemm_epilogue_kernel(
    const unsigned short* __restrict__ Xb,   // [2048][512] bf16 bits
    const unsigned short* __restrict__ Qb,   // [24576][512] bf16 bits
    const int* __restrict__ targets,
    const int* __restrict__ q_targets,
    const int* __restrict__ order_p,
    float* __restrict__ P) {                 // [NBLK][N_ROWS] partial sums

    __shared__ unsigned short As[BM * BK];   // 16 KB
    __shared__ unsigned short Bs[BN * BK];   // 16 KB

    const int tid  = threadIdx.x;
    const int lane = tid & 63;
    const int wave = tid >> 6;               // 0..3
    const int wm = wave >> 1, wn = wave & 1;
    const int quad = lane >> 4;              // 0..3
    const int l15  = lane & 15;
    const int l7   = l15 & 7;                // row mod 8 for swizzle

    // grid: x = row block (16), y = col block (192). Consecutive linear
    // block IDs share the same B slab -> better per-XCD L2 reuse of Q.
    const int m0 = blockIdx.x * BM;
    const int n0 = blockIdx.y * BN;

    f32x4 acc[4][4];
    #pragma unroll
    for (int i = 0; i < 4; i++)
        #pragma unroll
        for (int j = 0; j < 4; j++)
            acc[i][j] = (f32x4){0.f, 0.f, 0.f, 0.f};

    // Staging: chunk = wave*4+j covers rows chunk*8..+7. Lane l stages
    // global row chunk*8 + (l>>3), 16B-chunk cg = (l&7) ^ (l>>3) -- the
    // inverse of the read-side swizzle. LDS dest = base + lane*16 B (fixed).
    const int stR = (lane >> 3);                       // 0..7
    const int stC = ((lane & 7) ^ stR) * 8;            // swizzled 16B chunk

    for (int k0 = 0; k0 < DIM; k0 += BK) {
        #pragma unroll
        for (int j = 0; j < 4; j++) {
            int chunk = wave * 4 + j;                 // 0..15
            int R = chunk * 8 + stR;                  // 0..127
            const unsigned short* ga = Xb + (size_t)(m0 + R) * DIM + k0 + stC;
            const unsigned short* gb = Qb + (size_t)(n0 + R) * DIM + k0 + stC;
            __builtin_amdgcn_global_load_lds(
                (const __attribute__((address_space(1))) unsigned int*)ga,
                (__attribute__((address_space(3))) unsigned int*)&As[chunk * 512 + lane * 8],
                16, 0, 0);
            __builtin_amdgcn_global_load_lds(
                (const __attribute__((address_space(1))) unsigned int*)gb,
                (__attribute__((address_space(3))) unsigned int*)&Bs[chunk * 512 + lane * 8],
                16, 0, 0);
        }
        __syncthreads();

        #pragma unroll
        for (int ks = 0; ks < BK; ks += 32) {
            short8 a[4], b[4];
            #pragma unroll
            for (int mt = 0; mt < 4; mt++)
                a[mt] = *(const short8*)&As[(wm * 64 + mt * 16 + l15) * BK
                                            + ((((ks >> 3) + quad) ^ l7) << 3)];
            #pragma unroll
            for (int nt = 0; nt < 4; nt++)
                b[nt] = *(const short8*)&Bs[(wn * 64 + nt * 16 + l15) * BK
                                            + ((((ks >> 3) + quad) ^ l7) << 3)];
            #pragma unroll
            for (int mt = 0; mt < 4; mt++)
                #pragma unroll
                for (int nt = 0; nt < 4; nt++)
                    acc[mt][nt] = __builtin_amdgcn_mfma_f32_16x16x32_bf16(
                        a[mt], b[nt], acc[mt][nt], 0, 0, 0);
        }
        __syncthreads();
    }

    // ---- Epilogue: exp + mask + block row-reduction, no atomics ----
    const int ord  = order_p[0];
    const int qIdx = n0 / KQ;            // block lies entirely within one queue
    const bool isOrd = (qIdx == ord);
    const int kbase = n0 - qIdx * KQ;

    int qtv[4] = {0, 0, 0, 0};
    if (isOrd) {
        #pragma unroll
        for (int nt = 0; nt < 4; nt++)
            qtv[nt] = q_targets[ord * KQ + kbase + wn * 64 + nt * 16 + l15];
    }

    // Reuse As space (all waves past final __syncthreads of the K-loop).
    float* red = (float*)As;             // red[wn*128 + local_row], 1 KB

    #pragma unroll
    for (int mt = 0; mt < 4; mt++) {
        int rowl = wm * 64 + mt * 16 + quad * 4;        // local row base
        int tg[4] = {0, 0, 0, 0};
        if (isOrd) {
            #pragma unroll
            for (int reg = 0; reg < 4; reg++) tg[reg] = targets[m0 + rowl + reg];
        }
        #pragma unroll
        for (int reg = 0; reg < 4; reg++) {
            float s = 0.f;
            #pragma unroll
            for (int nt = 0; nt < 4; nt++) {
                float sim = acc[mt][nt][reg];
                float e = __expf(4.0f * sim - 4.0f);
                if (isOrd && tg[reg] == qtv[nt]) e = 0.f;  // masked entry
                s += e;
            }
            // reduce over the 16 columns held across lanes of this quad
            s += __shfl_xor(s, 1, 64);
            s += __shfl_xor(s, 2, 64);
            s += __shfl_xor(s, 4, 64);
            s += __shfl_xor(s, 8, 64);
            if (l15 == 0)
                red[wn * 128 + rowl + reg] = s;
        }
    }
    __syncthreads();
    if (tid < 128)
        P[(size_t)blockIdx.y * N_ROWS + m0 + tid] = red[tid] + red[128 + tid];
}

// ---------------------------------------------------------------------------
// Kernel 3: per-row total = sum over 192 partials (coalesced), count via
// per-wave ballot histogram (round-2: 8192 contended LDS atomics per block
// serialized ~512-deep per bin -> replaced with ballot+popcount, 64 atomics
// per block), then accumulate mean(log(total/cnt)) into pre-zeroed out.
// ---------------------------------------------------------------------------
__global__ __launch_bounds__(256) void reduce_kernel(
    const float* __restrict__ P,
    const int* __restrict__ targets,
    const int* __restrict__ q_targets,
    const int* __restrict__ order_p,
    float* __restrict__ out) {
    __shared__ int hist[NCLASS];
    __shared__ float partial[4];
    int tid = threadIdx.x;
    int wave = tid >> 6, lane = tid & 63;
    if (tid < NCLASS) hist[tid] = 0;
    __syncthreads();
    int ord = order_p[0];

    int local[NCLASS];
    #pragma unroll
    for (int c = 0; c < NCLASS; c++) local[c] = 0;
    for (int i = tid; i < KQ; i += 256) {           // 32 iterations
        int v = q_targets[ord * KQ + i];
        #pragma unroll
        for (int c = 0; c < NCLASS; c++)
            local[c] += __popcll(__ballot(v == c)); // wave-uniform count
    }
    if (lane == 0) {
        #pragma unroll
        for (int c = 0; c < NCLASS; c++)
            atomicAdd(&hist[c], local[c]);
    }
    __syncthreads();

    int r = blockIdx.x * 256 + tid;      // 8 blocks x 256 = 2048 rows
    float total = 0.f;
    for (int nb = 0; nb < NBLK; nb++)
        total += P[(size_t)nb * N_ROWS + r];   // coalesced across threads
    float cnt = (float)(QN * KQ - hist[targets[r]]);
    float v = logf(total / cnt);

    #pragma unroll
    for (int off = 1; off < 64; off <<= 1)
        v += __shfl_xor(v, off, 64);
    if (lane == 0) partial[wave] = v;
    __syncthreads();
    if (tid == 0)
        atomicAdd(out, (partial[0] + partial[1] + partial[2] + partial[3])
                       * (1.0f / (float)N_ROWS));
}

// ---------------------------------------------------------------------------
extern "C" void kernel_launch(void* const* d_in, const int* in_sizes, int n_in,
                              void* d_out, int out_size, void* d_ws, size_t ws_size,
                              hipStream_t stream) {
    const float* x         = (const float*)d_in[0];
    const float* q         = (const float*)d_in[1];
    const int*   targets   = (const int*)d_in[2];
    const int*   q_targets = (const int*)d_in[3];
    const int*   order     = (const int*)d_in[4];
    float* out = (float*)d_out;

    // Workspace: P (192*2048 f32 = 1.5 MB) | Xb (2 MB bf16) | Qb (24 MB bf16)
    char* ws = (char*)d_ws;
    float* P = (float*)ws;
    unsigned short* Xb = (unsigned short*)(ws + (size_t)NBLK * N_ROWS * 4);
    unsigned short* Qb = Xb + (size_t)N_ROWS * DIM;

    hipMemsetAsync(out, 0, sizeof(float), stream);

    norm_cast_kernel<<<(N_ROWS + NCOL) / 4, 256, 0, stream>>>(x, q, Xb, Qb);

    dim3 grid(N_ROWS / BM, NCOL / BN);   // x = row block, y = col block
    gemm_epilogue_kernel<<<grid, 256, 0, stream>>>(Xb, Qb, targets, q_targets, order, P);

    reduce_kernel<<<N_ROWS / 256, 256, 0, stream>>>(P, targets, q_targets, order, out);
}